// Round 18
// baseline (33.350 us; speedup 1.0000x reference)
//
#include <hip/hip_runtime.h>

// RoiAlign: fm (4,256,50,50) f32, boxes (512,4), box_idx (512) -> out (512,256,14,14) f32
//
// R18: PRODUCER/CONSUMER WAVE SPECIALIZATION.
// Evidence: stores-only 17.1us (R7), read/compute-only 12.5us (R12), every
// combined variant = ~30 = SUM (R11/14/16/17 all null). Coupling suspect:
// every wave that computes also stores, and all waits (vmcnt in-order,
// __syncthreads' implicit vmcnt(0), endpgm drain) chain CU work to HBM store
// completion. Fix: 6-wave blocks; waves 0-3 PRODUCE (DMA windows -> bilinear
// -> ds_write results; vmcnt queue = DMAs ONLY, never a store), waves 4-5
// CONSUME (ds_read_b128 -> global NT stores; never execute any vmcnt wait).
// Handoff: double-buffered result LDS + RAW s_barrier with manual lgkmcnt(0)
// (NOT __syncthreads -- that would reinsert the vmcnt(0) store drain).
// Skewed loop: iter j: produce(j) || consume(j-1). 4 items x 8 ch = box x
// 32-ch XCD slab (R9 mapping kept). Weight setup once per box. No divides.

typedef float f32x4 __attribute__((ext_vector_type(4)));

constexpr int C_DIM = 256;
constexpr int H_DIM = 50;
constexpr int W_DIM = 50;
constexpr int CW    = 14;
constexpr int NPOS  = 196;
constexpr int PLANE = H_DIM * W_DIM;
constexpr int WC    = 16;
constexpr int WSZ   = 256;            // 16x16 floats per plane window
constexpr float INV_STRIDE = 1.0f / 16.0f;
constexpr float INV13 = 1.0f / 13.0f;

struct SC { int bi, yLo, xW; float x1, y1, sx, sy; };
struct WT { int w00[4]; float wx[4], ox[4], wy[4], oy[4]; };

__device__ __forceinline__ SC mk_sc(const float* boxes, const int* bidx, int m) {
    float4 bx = reinterpret_cast<const float4*>(boxes)[m];
    SC s;
    s.bi = bidx[m];
    s.x1 = bx.x * INV_STRIDE;
    s.y1 = bx.y * INV_STRIDE;
    s.sx = (bx.z * INV_STRIDE - s.x1) * INV13;
    s.sy = (bx.w * INV_STRIDE - s.y1) * INV13;
    int xLo = min(max((int)floorf(s.x1), 0), W_DIM - 1);
    s.yLo = min(max((int)floorf(s.y1), 0), H_DIM - 1);
    s.xW  = min(xLo, W_DIM - WC);
    return s;
}

__device__ __forceinline__ void mk_wt(const SC& s, int q, WT& W) {
    #pragma unroll
    for (int e = 0; e < 4; ++e) {
        int p  = 4 * q + e;
        int iy = p / CW;
        int ix = p - iy * CW;
        float ys = s.y1 + (float)iy * s.sy;
        float xs = s.x1 + (float)ix * s.sx;
        float y0f = floorf(ys);
        float x0f = floorf(xs);
        float wy = ys - y0f;
        float wx = xs - x0f;
        int y0i = min(max((int)y0f, 0), H_DIM - 1);
        int x0i = min(max((int)x0f, 0), W_DIM - 1);
        bool v = (ys >= 0.0f) && (ys <= (float)(H_DIM - 1)) &&
                 (xs >= 0.0f) && (xs <= (float)(W_DIM - 1));
        W.w00[e] = (y0i - s.yLo) * WC + (x0i - s.xW);
        W.wx[e] = v ? wx : 0.0f;       // invalid -> both x-weights 0 -> exact 0
        W.ox[e] = v ? (1.0f - wx) : 0.0f;
        W.wy[e] = wy; W.oy[e] = 1.0f - wy;
    }
}

// stage 2 plane-windows (producer wave p's channels of item j) via async DMA
__device__ __forceinline__ void stageP(const float* fm, const SC& s, int gch,
                                       int l, float* wbuf) {
    int row  = l >> 2;
    int quad = l & 3;
    int gy   = min(s.yLo + row, H_DIM - 1);
    const float* g0 = fm + ((size_t)(s.bi * C_DIM + gch)) * PLANE
                         + gy * W_DIM + s.xW + quad * 4;
    __builtin_amdgcn_global_load_lds(
        (const __attribute__((address_space(1))) unsigned int*)g0,
        (__attribute__((address_space(3))) unsigned int*)wbuf, 16, 0, 0);
    __builtin_amdgcn_global_load_lds(
        (const __attribute__((address_space(1))) unsigned int*)(g0 + PLANE),
        (__attribute__((address_space(3))) unsigned int*)(wbuf + WSZ), 16, 0, 0);
}

__global__ __launch_bounds__(384) void roi_align_v18(
    const float* __restrict__ fm,
    const float* __restrict__ boxes,
    const int*   __restrict__ box_idx,
    float*       __restrict__ out)
{
    __shared__ float WBuf[4][2][2 * WSZ];   // 16 KB: per-producer-wave dbuf
    __shared__ float RBuf[2][8 * NPOS];     // 12.25 KB: result dbuf (8 ch)

    int bid  = blockIdx.x;
    int xcd  = bid & 7;                     // R9 slab: XCD k owns ch [32k,32k+32)
    int m    = bid >> 3;                    // box 0..511
    int cb_x = xcd * 32;

    int t  = threadIdx.x;
    int wv = t >> 6;                        // 0..3 producers, 4..5 consumers
    int l  = t & 63;

    SC s = mk_sc(boxes, box_idx, m);
    WT W;
    if (wv < 4) {
        mk_wt(s, min(l, 48), W);
        // prologue: DMA item 0 (this wave's 2 channels)
        stageP(fm, s, cb_x + 0 * 8 + wv * 2, l, &WBuf[wv][0][0]);
    }

    // skewed loop: iter j: produce(j) || consume(j-1); raw barrier each iter.
    #pragma unroll
    for (int j = 0; j <= 4; ++j) {
        if (wv < 4 && j < 4) {
            // prefetch item j+1 windows (wave-private other buffer)
            if (j < 3)
                stageP(fm, s, cb_x + (j + 1) * 8 + wv * 2, l,
                       &WBuf[wv][(j + 1) & 1][0]);
            // wait own DMAs for item j (producer vmem queue = DMAs ONLY)
            if (j < 3) asm volatile("s_waitcnt vmcnt(2)" ::: "memory");
            else       asm volatile("s_waitcnt vmcnt(0)" ::: "memory");

            if (l < 49) {
                #pragma unroll
                for (int k = 0; k < 2; ++k) {
                    const float* wp = &WBuf[wv][j & 1][k * WSZ];
                    float rv[4];
                    #pragma unroll
                    for (int e = 0; e < 4; ++e) {
                        float f00 = wp[W.w00[e]];
                        float f01 = wp[W.w00[e] + 1];
                        float f10 = wp[W.w00[e] + WC];
                        float f11 = wp[W.w00[e] + WC + 1];
                        float top = f00 * W.ox[e] + f01 * W.wx[e];
                        float bot = f10 * W.ox[e] + f11 * W.wx[e];
                        rv[e] = top * W.oy[e] + bot * W.wy[e];
                    }
                    f32x4 r;
                    r.x = rv[0]; r.y = rv[1]; r.z = rv[2]; r.w = rv[3];
                    *reinterpret_cast<f32x4*>(
                        &RBuf[j & 1][(wv * 2 + k) * NPOS + l * 4]) = r;
                }
            }
            // make ds_writes visible before the barrier (manual, no vmcnt!)
            asm volatile("s_waitcnt lgkmcnt(0)" ::: "memory");
        }

        if (wv >= 4 && j >= 1) {
            // consume item j-1: pure LDS read -> global store; NO vmcnt waits.
            int b = (j - 1) & 1;
            if (l < 49) {
                #pragma unroll
                for (int k = 0; k < 4; ++k) {
                    int ch = (wv - 4) * 4 + k;            // 0..7 within item
                    f32x4 v = *reinterpret_cast<const f32x4*>(
                        &RBuf[b][ch * NPOS + l * 4]);
                    float* op = out + ((size_t)(m * C_DIM + cb_x + (j - 1) * 8
                                                + ch)) * NPOS + l * 4;
                    __builtin_nontemporal_store(v, reinterpret_cast<f32x4*>(op));
                }
            }
            // ds_reads already retired (compiler waits before use); stores
            // stay in flight across the raw barrier.
        }

        // RAW barrier: does NOT drain vmcnt (consumer stores keep flowing).
        asm volatile("" ::: "memory");
        __builtin_amdgcn_s_barrier();
        asm volatile("" ::: "memory");
    }
}

extern "C" void kernel_launch(void* const* d_in, const int* in_sizes, int n_in,
                              void* d_out, int out_size, void* d_ws, size_t ws_size,
                              hipStream_t stream) {
    const float* fm      = (const float*)d_in[0];
    const float* boxes   = (const float*)d_in[1];
    const int*   box_idx = (const int*)d_in[2];
    float* out = (float*)d_out;

    dim3 block(384);           // 4 producer + 2 consumer waves
    dim3 grid(512 * 8);        // (box, xcd-slab); R9 channel-slab mapping
    hipLaunchKernelGGL(roi_align_v18, grid, block, 0, stream,
                       fm, boxes, box_idx, out);
}

// Round 20
// 30.030 us; speedup vs baseline: 1.1106x; 1.1106x over previous
//
#include <hip/hip_runtime.h>

// RoiAlign: fm (4,256,50,50) f32, boxes (512,4), box_idx (512) -> out (512,256,14,14) f32
//
// R20: == R11 (best, 29.95us) + ROW-TIERED STAGING (fabric-byte probe, done
// with PROVEN mechanics this time).
// R19's width=12 global_load_lds FAILED correctness (absmax 1e4): width 12's
// LDS layout is not the assumed lane*12 linear (only 4 and 16 are HW-verified
// per the guide, m03/m97). Reverted to width=16 everywhere.
// Model A under test: shared L2-fabric r+w bandwidth ~8 TB/s is the wall
// (store-only 5.9 TB/s, read-only 10.5 TB/s, combined 7.7 TB/s, additive).
// Byte cut via ROWS: y-tap span <= (floor(y2)+1 - floor(y1)) + 1 rows; pick
// block-uniform nrows in {8,12,16} (span<=6 -> 8, <=10 -> 12, else 16; 1-row
// slack each) and predicate the DMA on row < nrows (exec-masked lanes skip
// global read AND LDS write; m104 layout untouched, stride stays 16).
// Expected reads 131 -> ~97 MB. PREDICTION: Model A -> ~26us; null -> plateau.
// Safety: w00 = vld ? w00 : 0 so invalid samples never read unstaged LDS rows.
// Everything else == R11: channel-slab XCD tiling; wave-autonomous DMA + own
// vmcnt(0); validity folded into x-weights; quad dwordx4 NT stores.

typedef float f32x4 __attribute__((ext_vector_type(4)));

constexpr int C_DIM = 256;
constexpr int H_DIM = 50;
constexpr int W_DIM = 50;
constexpr int M_BOX = 512;
constexpr int CW    = 14;
constexpr int NPOS  = 196;            // 14*14 output positions
constexpr int CCH   = 16;             // channels per block (4 waves x 4)
constexpr int PLANE  = H_DIM * W_DIM; // 2500
constexpr int WC  = 16;               // window cols / LDS row stride
constexpr int WSZ = 256;              // 16x16 window floats per plane
constexpr float INV_STRIDE = 1.0f / 16.0f;

__global__ __launch_bounds__(256) void roi_align_v20(
    const float* __restrict__ fm,
    const float* __restrict__ boxes,
    const int*   __restrict__ box_idx,
    float*       __restrict__ out)
{
    __shared__ float Wnd[CCH * WSZ];  // 16 KB -> 8 blocks/CU

    // Channel-slab XCD mapping (R9): XCD k = bid&7 owns channels [32k, 32k+32).
    int bid   = blockIdx.x;
    int xcd   = bid & 7;
    int w     = bid >> 3;             // [0,1024)
    int m     = w >> 1;               // box
    int cbase = xcd * 32 + (w & 1) * CCH;

    int t  = threadIdx.x;
    int wv = t >> 6;                  // wave 0..3 -> channels cbase+4wv..+3
    int l  = t & 63;

    float4 bx = reinterpret_cast<const float4*>(boxes)[m];
    int bi = box_idx[m];
    float x1 = bx.x * INV_STRIDE;
    float y1 = bx.y * INV_STRIDE;
    float x2 = bx.z * INV_STRIDE;
    float y2 = bx.w * INV_STRIDE;

    int xLo = min(max((int)floorf(x1), 0), W_DIM - 1);
    int yLo = min(max((int)floorf(y1), 0), H_DIM - 1);
    int xW  = min(xLo, W_DIM - WC);   // window cols xW..xW+15 always in-bounds

    // Row tier: max valid y-tap = min(clip(floor(y2))+1, 49); need
    // (ymax-yLo) <= nrows-1 rows with 1-row slack -> thresholds 6/10.
    int ymax = min(min(max((int)floorf(y2), 0), H_DIM - 1) + 1, H_DIM - 1);
    int span = ymax - yLo;
    int nrows = (span <= 6) ? 8 : ((span <= 10) ? 12 : 16);

    // ---- Phase A: wave stages ITS OWN 4 plane-windows (async DMA) ----
    {
        int row  = l >> 2;            // 0..15
        int quad = l & 3;             // cols 4quad..4quad+3
        int gy   = min(yLo + row, H_DIM - 1);   // row clamp-duplicate
        const float* g0 = fm + ((size_t)(bi * C_DIM + cbase + wv * 4)) * PLANE
                             + gy * W_DIM + xW + quad * 4;
        if (row < nrows) {            // exec-masked: lanes beyond nrows idle
            #pragma unroll
            for (int k = 0; k < 4; ++k) {
                const float* g  = g0 + (size_t)k * PLANE;
                float*       l0 = &Wnd[(wv * 4 + k) * WSZ];  // wave-uniform base
                __builtin_amdgcn_global_load_lds(
                    (const __attribute__((address_space(1))) unsigned int*)g,
                    (__attribute__((address_space(3))) unsigned int*)l0,
                    16, 0, 0);
            }
        }
    }

    // ---- Phase B: lanes 0..48 each own a position-quad x wave's 4 channels ----
    if (l < 49) {
        int q = l;                    // quad -> positions 4q..4q+3

        int   w00[4];
        float wxv[4], owx[4], wyv[4], owy[4];
        #pragma unroll
        for (int e = 0; e < 4; ++e) {
            int p  = 4 * q + e;
            int iy = p / CW;
            int ix = p - iy * CW;
            // reference op order: v1 + (i * (v2-v1)) / 13
            float ys = y1 + ((float)iy * (y2 - y1)) / 13.0f;
            float xs = x1 + ((float)ix * (x2 - x1)) / 13.0f;
            float y0f = floorf(ys);
            float x0f = floorf(xs);
            float wy = ys - y0f;
            float wx = xs - x0f;
            int y0i = min(max((int)y0f, 0), H_DIM - 1);
            int x0i = min(max((int)x0f, 0), W_DIM - 1);
            bool vld = (ys >= 0.0f) && (ys <= (float)(H_DIM - 1)) &&
                       (xs >= 0.0f) && (xs <= (float)(W_DIM - 1));
            // invalid -> index 0 (always-staged row) AND zero x-weights ->
            // taps finite, result exact 0.  Valid taps are within nrows rows.
            w00[e] = vld ? ((y0i - yLo) * WC + (x0i - xW)) : 0;
            wxv[e] = vld ? wx : 0.0f;
            owx[e] = vld ? (1.0f - wx) : 0.0f;
            wyv[e] = wy; owy[e] = 1.0f - wy;
        }

        // wait for THIS WAVE's 4 DMA loads only (no cross-wave drain)
        asm volatile("s_waitcnt vmcnt(0)" ::: "memory");

        const float* wp = &Wnd[(size_t)(wv * 4) * WSZ];
        float* op = out + ((size_t)m * C_DIM + cbase + wv * 4) * NPOS + 4 * q;

        #pragma unroll
        for (int k = 0; k < 4; ++k) {
            float rv[4];
            #pragma unroll
            for (int e = 0; e < 4; ++e) {
                float f00 = wp[w00[e]];
                float f01 = wp[w00[e] + 1];
                float f10 = wp[w00[e] + WC];
                float f11 = wp[w00[e] + WC + 1];
                float top = f00 * owx[e] + f01 * wxv[e];
                float bot = f10 * owx[e] + f11 * wxv[e];
                rv[e] = top * owy[e] + bot * wyv[e];
            }
            f32x4 r;
            r.x = rv[0]; r.y = rv[1]; r.z = rv[2]; r.w = rv[3];
            __builtin_nontemporal_store(r, reinterpret_cast<f32x4*>(op));
            wp += WSZ;
            op += NPOS;
        }
    }
}

extern "C" void kernel_launch(void* const* d_in, const int* in_sizes, int n_in,
                              void* d_out, int out_size, void* d_ws, size_t ws_size,
                              hipStream_t stream) {
    const float* fm      = (const float*)d_in[0];
    const float* boxes   = (const float*)d_in[1];
    const int*   box_idx = (const int*)d_in[2];
    float* out = (float*)d_out;

    dim3 block(256);
    dim3 grid(M_BOX * (C_DIM / CCH) /* 8192 */);
    hipLaunchKernelGGL(roi_align_v20, grid, block, 0, stream,
                       fm, boxes, box_idx, out);
}